// Round 5
// baseline (159.544 us; speedup 1.0000x reference)
//
#include <hip/hip_runtime.h>
#include <stdint.h>

typedef unsigned long long u64;
typedef unsigned int u32;
typedef u32 v4u __attribute__((ext_vector_type(4)));

#define K_MSG   1024
#define N_CODE  2048
#define NB      32768
#define KW      16        // 1024 bits / 64 = 16 u64 words per row/col
#define ROWS_TILE 256     // rows staged per block: 256 * 128B = 32 KB LDS
#define COLS_PER_BLOCK 256

// ---------------- pack b: [NB][K_MSG] int32 -> [NB][KW] u64 ----------------
__global__ void pack_b_kernel(const int* __restrict__ b, u64* __restrict__ bp,
                              int nwords) {
    const int lane  = threadIdx.x & 63;
    const int wave  = blockIdx.x * (blockDim.x >> 6) + (threadIdx.x >> 6);
    const int nwave = gridDim.x * (blockDim.x >> 6);
    for (int word = wave; word < nwords; word += nwave) {
        int v = b[(size_t)word * 64 + lane];
        u64 m = __ballot((v & 1) != 0);
        if (lane == 0) bp[word] = m;
    }
}

// ---------------- pack G: Gp[w][j], bit t = G[w*64+t][j] --------------------
__global__ void pack_g_kernel(const int* __restrict__ G, u64* __restrict__ gp) {
    const int lane = threadIdx.x & 63;
    const int wave = blockIdx.x * (blockDim.x >> 6) + (threadIdx.x >> 6); // 0..511
    const int w    = wave >> 5;   // 0..15
    const int jb   = wave & 31;   // 0..31
    const int j    = jb * 64 + lane;
    u64 word = 0;
#pragma unroll 16
    for (int t = 0; t < 64; ++t) {
        int v = G[(size_t)(w * 64 + t) * N_CODE + j];
        word |= (u64)(v & 1) << t;
    }
    gp[(size_t)w * N_CODE + j] = word;
}

// ---------------- main ------------------------------------------------------
// Block 256 thr; lane owns ONE column j; all waves share a 256-row tile staged
// in LDS (32 KB). Per row: 8x ds_read_b128 broadcast (uniform addr -> no bank
// conflict, in-order returns -> compiler pipelines with counted lgkmcnt) +
// AND/XOR tree + coalesced dword store. No asm, no full drains.
__global__ __launch_bounds__(256, 4) void encode_main(const u64* __restrict__ bp,
                                                      const u64* __restrict__ gp,
                                                      int* __restrict__ out) {
    __shared__ u32 rows[ROWS_TILE * 32];   // 32 KB

    const int tid = threadIdx.x;
    const int j   = blockIdx.x * COLS_PER_BLOCK + tid;
    const int r0  = blockIdx.y * ROWS_TILE;

    // this lane's column words: 32 u32 in VGPRs
    u32 g[32];
#pragma unroll
    for (int w = 0; w < KW; ++w) {
        u64 v = gp[(size_t)w * N_CODE + j];
        g[2 * w]     = (u32)v;
        g[2 * w + 1] = (u32)(v >> 32);
    }

    // stage the row tile: contiguous 32 KB of bp starting at row r0
    {
        const v4u* __restrict__ src = (const v4u*)(bp + ((size_t)r0 << 4));
        v4u* dst = (v4u*)rows;
#pragma unroll
        for (int i = 0; i < 8; ++i)
            dst[tid + COLS_PER_BLOCK * i] = src[tid + COLS_PER_BLOCK * i];
    }
    __syncthreads();

    int* __restrict__ op = out + (size_t)r0 * N_CODE + j;

#pragma unroll 2
    for (int r = 0; r < ROWS_TILE; ++r) {
        const u32* rw = &rows[r * 32];
        u32 a0 = 0, a1 = 0, a2 = 0, a3 = 0;
#pragma unroll
        for (int i = 0; i < 8; ++i) {
            a0 ^= rw[i]      & g[i];
            a1 ^= rw[8 + i]  & g[8 + i];
            a2 ^= rw[16 + i] & g[16 + i];
            a3 ^= rw[24 + i] & g[24 + i];
        }
        u32 acc = (a0 ^ a1) ^ (a2 ^ a3);
        op[(size_t)r * N_CODE] = (int)(__popc(acc) & 1);
    }
}

// ---------------- fallback (only if ws too small) ---------------------------
__global__ void encode_naive(const int* __restrict__ b, const int* __restrict__ G,
                             int* __restrict__ out) {
    size_t idx = (size_t)blockIdx.x * blockDim.x + threadIdx.x;
    size_t total = (size_t)NB * N_CODE;
    if (idx >= total) return;
    int i = (int)(idx / N_CODE);
    int j = (int)(idx % N_CODE);
    int acc = 0;
    for (int k = 0; k < K_MSG; ++k)
        acc ^= b[(size_t)i * K_MSG + k] & G[(size_t)k * N_CODE + j];
    out[idx] = acc & 1;
}

extern "C" void kernel_launch(void* const* d_in, const int* in_sizes, int n_in,
                              void* d_out, int out_size, void* d_ws, size_t ws_size,
                              hipStream_t stream) {
    const int* b = (const int*)d_in[0];
    const int* G = (const int*)d_in[1];
    int* out = (int*)d_out;

    const size_t bp_bytes = (size_t)NB * KW * sizeof(u64);      // 4 MiB
    const size_t gp_bytes = (size_t)N_CODE * KW * sizeof(u64);  // 256 KiB

    if (ws_size < bp_bytes + gp_bytes) {
        size_t total = (size_t)NB * N_CODE;
        encode_naive<<<(unsigned)((total + 255) / 256), 256, 0, stream>>>(b, G, out);
        return;
    }

    u64* bp = (u64*)d_ws;
    u64* gp = (u64*)((char*)d_ws + bp_bytes);

    pack_b_kernel<<<2048, 256, 0, stream>>>(b, bp, NB * KW);
    pack_g_kernel<<<128, 256, 0, stream>>>(G, gp);

    dim3 grid(N_CODE / COLS_PER_BLOCK, NB / ROWS_TILE);  // 8 x 128 = 1024 blocks
    encode_main<<<grid, 256, 0, stream>>>(bp, gp, out);
}